// Round 3
// baseline (66.528 us; speedup 1.0000x reference)
//
#include <hip/hip_runtime.h>
#include <hip/hip_bf16.h>
#include <hip/hip_fp16.h>

typedef short short8 __attribute__((ext_vector_type(8)));
typedef float f32x4 __attribute__((ext_vector_type(4)));

#define B_ 4
#define C_ 64
#define O_ 64
#define H_ 128
#define W_ 128
#define HT 8    // tile rows
#define WT 16   // tile cols
#define RS 16   // staged rows (HT + 2*4 halo)
#define CS 24   // staged cols (WT + 2*4 halo)
// xs layout: [row][col][ch], ch-stride 72 bf16 = 144B = 9 uint4 slots per (row,col)

__device__ __forceinline__ float b2f(unsigned short h) {
  return __uint_as_float(((unsigned int)h) << 16);
}
__device__ __forceinline__ unsigned short f2b(float x) {
  unsigned int u = __float_as_uint(x);
  u += 0x7fffu + ((u >> 16) & 1u);
  return (unsigned short)(u >> 16);
}

// ---------------------------------------------------------------------------
// Kernel 0: pre-build fragment-ready bf16 weights in workspace.
//  wf  (deform_w): 18 k-steps x 4 o-tiles x 64 lanes x 8 = 36864 bf16
//     k-order: k = kk*64 + c ; s = kk*2 + ch ; lane holds A[o=ot*16+(l&15)][k0+(l>>4)*8+j]
//  wfm (mask_w padded to 16 rows): 18 k-steps x 64 lanes x 8 = 9216 bf16
//     k-order: k = tap*64 + c
// ---------------------------------------------------------------------------
__global__ void build_frags(const float* __restrict__ dw,
                            const float* __restrict__ mw,
                            __hip_bfloat16* __restrict__ wsb) {
  int t = blockIdx.x * 256 + threadIdx.x;
  if (t < 36864) {
    int j = t & 7, lane = (t >> 3) & 63, ot = (t >> 9) & 3, s = t >> 11;
    int kk = s >> 1, ch = s & 1;
    int o = ot * 16 + (lane & 15);
    int c = ch * 32 + ((lane >> 4) << 3) + j;
    wsb[t] = __float2bfloat16(dw[(o * 64 + c) * 9 + kk]);
  } else if (t < 46080) {
    int t2 = t - 36864;
    int j = t2 & 7, lane = (t2 >> 3) & 63, s = t2 >> 9;
    int km = lane & 15;
    int c = (s & 1) * 32 + ((lane >> 4) << 3) + j;
    int tap = s >> 1;
    float v = (km < 9) ? mw[(km * 64 + c) * 9 + tap] : 0.0f;
    wsb[t] = __float2bfloat16(v);
  }
}

// ---------------------------------------------------------------------------
// Main fused kernel. One block per (batch, 8x16 pixel tile). 512 blocks total.
// LDS budget: 55296 (xs4) + 4608 (offl fp16) + 4608 (maskl) = 64512 B < 64 KiB
// ---------------------------------------------------------------------------
__global__ __launch_bounds__(256, 2)
void deform_main(const float* __restrict__ x,
                 const float* __restrict__ ele,
                 const float* __restrict__ ow,
                 const float* __restrict__ ob,
                 const float* __restrict__ mb,
                 const __hip_bfloat16* __restrict__ wsb,
                 float* __restrict__ out) {
  __shared__ uint4 xs4[RS * CS * 9];     // 55296 B
  __shared__ __half offl[128 * 18];      //  4608 B
  __shared__ float maskl[128 * 9];       //  4608 B

  const int tid = threadIdx.x;
  const int lane = tid & 63;
  const int wv = tid >> 6;
  const int pcl = lane & 15;
  const int lq = lane >> 4;

  const int bid = blockIdx.x;
  const int b = bid >> 7;
  const int t7 = bid & 127;
  const int r0 = (t7 >> 3) * HT;   // 16 row-tiles
  const int c0 = (t7 & 7) * WT;    // 8 col-tiles

  // ---- Phase 1: stage x patch to LDS as bf16 (zero-filled outside image) ----
  {
    __hip_bfloat16* xsb = (__hip_bfloat16*)xs4;
    const float* xb = x + b * (C_ * H_ * W_);
    for (int i = tid; i < RS * CS * 64; i += 256) {
      int c = i / (RS * CS);
      int rem = i - c * (RS * CS);
      int row = rem / CS;
      int col = rem - row * CS;
      int gy = r0 - 4 + row, gx = c0 - 4 + col;
      float v = 0.0f;
      if ((unsigned)gy < 128u && (unsigned)gx < 128u)
        v = xb[(c << 14) + (gy << 7) + gx];
      xsb[(row * CS + col) * 72 + c] = __float2bfloat16(v);
    }
  }
  __syncthreads();

  // ---- Phase 2: offset conv (1->18ch 3x3), threads < 128, one px each ----
  if (tid < 128) {
    int pr = tid >> 4, pc = tid & 15;
    int h = r0 + pr, w = c0 + pc;
    float ev[9];
#pragma unroll
    for (int ty = 0; ty < 3; ++ty)
#pragma unroll
      for (int tx = 0; tx < 3; ++tx) {
        int gy = h - 1 + ty, gx = w - 1 + tx;
        float v = 0.0f;
        if ((unsigned)gy < 128u && (unsigned)gx < 128u)
          v = ele[b * (H_ * W_) + (gy << 7) + gx];
        ev[ty * 3 + tx] = v;
      }
#pragma unroll
    for (int ci = 0; ci < 18; ++ci) {
      float a = ob[ci];
#pragma unroll
      for (int tap = 0; tap < 9; ++tap) a += ev[tap] * ow[ci * 9 + tap];
      offl[tid * 18 + ci] = __float2half(a);
    }
  }

  // ---- Phase 3: mask conv (64->9ch 3x3 + sigmoid) via MFMA ----
  {
    const uint4* wfm4 = ((const uint4*)wsb) + 4608;  // after 36864 bf16
    f32x4 macc0 = {0.f, 0.f, 0.f, 0.f};
    f32x4 macc1 = {0.f, 0.f, 0.f, 0.f};
#pragma unroll
    for (int s = 0; s < 18; ++s) {
      const int tap = s >> 1;
      const int chalf = s & 1;
      const int ty = tap / 3, tx = tap - ty * 3;
      short8 aw = *(const short8*)(wfm4 + (s * 64 + lane));
      const int csl = chalf * 4 + lq;
      {
        int pr = wv * 2 + 0;
        int rc = (pr + 3 + ty) * CS + (pcl + 3 + tx);
        short8 xv = *(const short8*)(xs4 + rc * 9 + csl);
        macc0 = __builtin_amdgcn_mfma_f32_16x16x32_bf16(aw, xv, macc0, 0, 0, 0);
      }
      {
        int pr = wv * 2 + 1;
        int rc = (pr + 3 + ty) * CS + (pcl + 3 + tx);
        short8 xv = *(const short8*)(xs4 + rc * 9 + csl);
        macc1 = __builtin_amdgcn_mfma_f32_16x16x32_bf16(aw, xv, macc1, 0, 0, 0);
      }
    }
#pragma unroll
    for (int pt = 0; pt < 2; ++pt) {
      int px = wv * 32 + pt * 16 + pcl;
      f32x4 m4 = pt ? macc1 : macc0;
#pragma unroll
      for (int r = 0; r < 4; ++r) {
        int km = lq * 4 + r;
        if (km < 9) {
          float a = m4[r] + mb[km];
          float m = 1.0f / (1.0f + __expf(-a));
          maskl[px * 9 + km] = m;
        }
      }
    }
  }
  __syncthreads();

  // ---- Phase 4: bilinear sampling (fragments built in registers) + MFMA ----
  const uint4* wf4 = (const uint4*)wsb;
  f32x4 acc[2][4];
#pragma unroll
  for (int pt = 0; pt < 2; ++pt)
#pragma unroll
    for (int ot = 0; ot < 4; ++ot) {
      f32x4 z = {0.f, 0.f, 0.f, 0.f};
      acc[pt][ot] = z;
    }

  for (int kk = 0; kk < 9; ++kk) {
    const int ky = kk / 3 - 1;
    const int kx = kk - (kk / 3) * 3 - 1;
    float a00[2], a01[2], a10[2], a11[2];
    int rc00[2], rc01[2], rc10[2], rc11[2];
#pragma unroll
    for (int pt = 0; pt < 2; ++pt) {
      int pr = wv * 2 + pt;
      int px = pr * 16 + pcl;
      int h = r0 + pr, w = c0 + pcl;
      float oy = __half2float(offl[px * 18 + kk * 2]);
      float ox = __half2float(offl[px * 18 + kk * 2 + 1]);
      float m = maskl[px * 9 + kk];
      float py = (float)(h + ky) + oy;
      float pxx = (float)(w + kx) + ox;
      float fy = floorf(py), fx = floorf(pxx);
      float wy = py - fy, wx = pxx - fx;
      int iy = (int)fy - r0 + 4;
      int ix = (int)fx - c0 + 4;
      int vy0 = (unsigned)iy < 16u;
      int vy1 = (unsigned)(iy + 1) < 16u;
      int vx0 = (unsigned)ix < 24u;
      int vx1 = (unsigned)(ix + 1) < 24u;
      int cy0 = min(max(iy, 0), 15), cy1 = min(max(iy + 1, 0), 15);
      int cx0 = min(max(ix, 0), 23), cx1 = min(max(ix + 1, 0), 23);
      float wy0 = 1.0f - wy, wx0 = 1.0f - wx;
      a00[pt] = wy0 * wx0 * m * (float)(vy0 & vx0);
      a01[pt] = wy0 * wx * m * (float)(vy0 & vx1);
      a10[pt] = wy * wx0 * m * (float)(vy1 & vx0);
      a11[pt] = wy * wx * m * (float)(vy1 & vx1);
      rc00[pt] = cy0 * CS + cx0;
      rc01[pt] = cy0 * CS + cx1;
      rc10[pt] = cy1 * CS + cx0;
      rc11[pt] = cy1 * CS + cx1;
    }
#pragma unroll
    for (int ch = 0; ch < 2; ++ch) {
      const int csl = ch * 4 + lq;
      short8 sf[2];
#pragma unroll
      for (int pt = 0; pt < 2; ++pt) {
        short8 v00 = *(const short8*)(xs4 + rc00[pt] * 9 + csl);
        short8 v01 = *(const short8*)(xs4 + rc01[pt] * 9 + csl);
        short8 v10 = *(const short8*)(xs4 + rc10[pt] * 9 + csl);
        short8 v11 = *(const short8*)(xs4 + rc11[pt] * 9 + csl);
        short8 t;
#pragma unroll
        for (int j = 0; j < 8; ++j) {
          float sv = a00[pt] * b2f((unsigned short)v00[j])
                   + a01[pt] * b2f((unsigned short)v01[j])
                   + a10[pt] * b2f((unsigned short)v10[j])
                   + a11[pt] * b2f((unsigned short)v11[j]);
          t[j] = (short)f2b(sv);
        }
        sf[pt] = t;
      }
      const int sidx = kk * 2 + ch;
#pragma unroll
      for (int ot = 0; ot < 4; ++ot) {
        short8 bw = *(const short8*)(wf4 + (sidx * 4 + ot) * 64 + lane);
#pragma unroll
        for (int pt = 0; pt < 2; ++pt)
          acc[pt][ot] = __builtin_amdgcn_mfma_f32_16x16x32_bf16(bw, sf[pt], acc[pt][ot], 0, 0, 0);
      }
    }
  }

  // ---- Epilogue: ReLU -> fp32 -> global ----
#pragma unroll
  for (int pt = 0; pt < 2; ++pt) {
    int pr = wv * 2 + pt;
    int h = r0 + pr;
    int w = c0 + pcl;
#pragma unroll
    for (int ot = 0; ot < 4; ++ot) {
#pragma unroll
      for (int r = 0; r < 4; ++r) {
        int o = ot * 16 + lq * 4 + r;
        float v = fmaxf(acc[pt][ot][r], 0.0f);
        out[((b * O_ + o) << 14) + (h << 7) + w] = v;
      }
    }
  }
}

extern "C" void kernel_launch(void* const* d_in, const int* in_sizes, int n_in,
                              void* d_out, int out_size, void* d_ws, size_t ws_size,
                              hipStream_t stream) {
  const float* x   = (const float*)d_in[0];
  const float* ele = (const float*)d_in[1];
  const float* ow  = (const float*)d_in[2];
  const float* ob  = (const float*)d_in[3];
  const float* mw  = (const float*)d_in[4];
  const float* mb  = (const float*)d_in[5];
  const float* dw  = (const float*)d_in[6];
  __hip_bfloat16* wsb = (__hip_bfloat16*)d_ws;

  build_frags<<<180, 256, 0, stream>>>(dw, mw, wsb);
  deform_main<<<512, 256, 0, stream>>>(x, ele, ow, ob, mb, wsb,
                                       (float*)d_out);
}

// Round 4
// 44.298 us; speedup vs baseline: 1.5018x; 1.5018x over previous
//
#include <hip/hip_runtime.h>
#include <hip/hip_bf16.h>
#include <hip/hip_fp16.h>

typedef short short8 __attribute__((ext_vector_type(8)));
typedef float f32x4 __attribute__((ext_vector_type(4)));

#define B_ 4
#define C_ 64
#define O_ 64
#define H_ 128
#define W_ 128
#define HT 8     // tile rows
#define WT 16    // tile cols
#define HALO 3
#define RS 14    // staged rows (HT + 2*HALO)
#define CS 22    // staged cols (WT + 2*HALO)
// xs layout: [row][col][ch], ch-stride 72 bf16 = 144B = 9 uint4 slots per (row,col)

__device__ __forceinline__ float b2f(unsigned short h) {
  return __uint_as_float(((unsigned int)h) << 16);
}
__device__ __forceinline__ short bfbits(float x) {
  __hip_bfloat16 h = __float2bfloat16(x);
  return __builtin_bit_cast(short, h);
}

// ---------------------------------------------------------------------------
// Kernel 0: pre-build fragment-ready bf16 weights in workspace.
//  wf  (deform_w): 18 k-steps x 4 o-tiles x 64 lanes x 8 = 36864 bf16
//     k-order: k = kk*64 + c ; s = kk*2 + ch ; lane holds A[o=ot*16+(l&15)][k0+(l>>4)*8+j]
//  wfm (mask_w padded to 16 rows): 18 k-steps x 64 lanes x 8 = 9216 bf16
//     k-order: k = tap*64 + c
// ---------------------------------------------------------------------------
__global__ void build_frags(const float* __restrict__ dw,
                            const float* __restrict__ mw,
                            __hip_bfloat16* __restrict__ wsb) {
  int t = blockIdx.x * 256 + threadIdx.x;
  if (t < 36864) {
    int j = t & 7, lane = (t >> 3) & 63, ot = (t >> 9) & 3, s = t >> 11;
    int kk = s >> 1, ch = s & 1;
    int o = ot * 16 + (lane & 15);
    int c = ch * 32 + ((lane >> 4) << 3) + j;
    wsb[t] = __float2bfloat16(dw[(o * 64 + c) * 9 + kk]);
  } else if (t < 46080) {
    int t2 = t - 36864;
    int j = t2 & 7, lane = (t2 >> 3) & 63, s = t2 >> 9;
    int km = lane & 15;
    int c = (s & 1) * 32 + ((lane >> 4) << 3) + j;
    int tap = s >> 1;
    float v = (km < 9) ? mw[(km * 64 + c) * 9 + tap] : 0.0f;
    wsb[t] = __float2bfloat16(v);
  }
}

// ---------------------------------------------------------------------------
// Main fused kernel. One block per (batch, 8x16 pixel tile). 512 blocks x
// 512 threads (8 waves; wave wv owns pixel row wv of the tile).
// LDS budget: 44352 (xs4) + 4608 (offl fp16) + 4608 (maskl) = 53568 B
// ---------------------------------------------------------------------------
__global__ __launch_bounds__(512, 4)
void deform_main(const float* __restrict__ x,
                 const float* __restrict__ ele,
                 const float* __restrict__ ow,
                 const float* __restrict__ ob,
                 const float* __restrict__ mb,
                 const __hip_bfloat16* __restrict__ wsb,
                 float* __restrict__ out) {
  __shared__ uint4 xs4[RS * CS * 9];     // 44352 B
  __shared__ __half offl[128 * 18];      //  4608 B
  __shared__ float maskl[128 * 9];       //  4608 B

  const int tid = threadIdx.x;
  const int lane = tid & 63;
  const int wv = tid >> 6;        // 0..7 = pixel row within tile
  const int pcl = lane & 15;      // pixel col within tile / MFMA col
  const int lq = lane >> 4;       // k-slice quadrant

  const int bid = blockIdx.x;
  const int b = bid >> 7;
  const int t7 = bid & 127;
  const int r0 = (t7 >> 3) * HT;   // 16 row-tiles
  const int c0 = (t7 & 7) * WT;    // 8 col-tiles

  // ---- Phase 1: stage x patch to LDS as bf16 (zero-filled outside image) ----
  {
    __hip_bfloat16* xsb = (__hip_bfloat16*)xs4;
    const float* xb = x + b * (C_ * H_ * W_);
    const int N = RS * CS * 64;           // 19712
    for (int i = tid; i < N; i += 512) {
      int c = i / (RS * CS);
      int rem = i - c * (RS * CS);
      int row = rem / CS;
      int col = rem - row * CS;
      int gy = r0 - HALO + row, gx = c0 - HALO + col;
      float v = 0.0f;
      if ((unsigned)gy < 128u && (unsigned)gx < 128u)
        v = xb[(c << 14) + (gy << 7) + gx];
      xsb[(row * CS + col) * 72 + c] = __float2bfloat16(v);
    }
  }
  __syncthreads();

  // ---- Phase 2: offset conv (1->18ch 3x3), threads < 128, one px each ----
  if (tid < 128) {
    int pr = tid >> 4, pc = tid & 15;
    int h = r0 + pr, w = c0 + pc;
    float ev[9];
#pragma unroll
    for (int ty = 0; ty < 3; ++ty)
#pragma unroll
      for (int tx = 0; tx < 3; ++tx) {
        int gy = h - 1 + ty, gx = w - 1 + tx;
        float v = 0.0f;
        if ((unsigned)gy < 128u && (unsigned)gx < 128u)
          v = ele[b * (H_ * W_) + (gy << 7) + gx];
        ev[ty * 3 + tx] = v;
      }
#pragma unroll
    for (int ci = 0; ci < 18; ++ci) {
      float a = ob[ci];
#pragma unroll
      for (int tap = 0; tap < 9; ++tap) a += ev[tap] * ow[ci * 9 + tap];
      offl[tid * 18 + ci] = __float2half(a);
    }
  }

  // ---- Phase 3: mask conv (64->9ch 3x3 + sigmoid) via MFMA; wave = row ----
  {
    const uint4* wfm4 = ((const uint4*)wsb) + 4608;  // after 36864 bf16
    f32x4 macc = {0.f, 0.f, 0.f, 0.f};
#pragma unroll
    for (int s = 0; s < 18; ++s) {
      const int tap = s >> 1;
      const int chalf = s & 1;
      const int ty = tap / 3, tx = tap - ty * 3;
      short8 aw = *(const short8*)(wfm4 + (s * 64 + lane));
      const int csl = chalf * 4 + lq;
      int rc = (wv + (HALO - 1) + ty) * CS + (pcl + (HALO - 1) + tx);
      short8 xv = *(const short8*)(xs4 + rc * 9 + csl);
      macc = __builtin_amdgcn_mfma_f32_16x16x32_bf16(aw, xv, macc, 0, 0, 0);
    }
    int px = wv * 16 + pcl;
#pragma unroll
    for (int r = 0; r < 4; ++r) {
      int km = lq * 4 + r;
      if (km < 9) {
        float a = macc[r] + mb[km];
        float m = 1.0f / (1.0f + __expf(-a));
        maskl[px * 9 + km] = m;
      }
    }
  }
  __syncthreads();

  // ---- Phase 4: bilinear sampling (fragments built in registers) + MFMA ----
  const uint4* wf4 = (const uint4*)wsb;
  f32x4 acc[4];
#pragma unroll
  for (int ot = 0; ot < 4; ++ot) {
    f32x4 z = {0.f, 0.f, 0.f, 0.f};
    acc[ot] = z;
  }

  const int px = wv * 16 + pcl;
  const int h = r0 + wv;
  const int w = c0 + pcl;

  for (int kk = 0; kk < 9; ++kk) {
    const int ky = kk / 3 - 1;
    const int kx = kk - (kk / 3) * 3 - 1;
    float oy = __half2float(offl[px * 18 + kk * 2]);
    float ox = __half2float(offl[px * 18 + kk * 2 + 1]);
    float m = maskl[px * 9 + kk];
    float py = (float)(h + ky) + oy;
    float pxx = (float)(w + kx) + ox;
    float fy = floorf(py), fx = floorf(pxx);
    float wy = py - fy, wx = pxx - fx;
    int iy = (int)fy - r0 + HALO;
    int ix = (int)fx - c0 + HALO;
    int vy0 = (unsigned)iy < (unsigned)RS;
    int vy1 = (unsigned)(iy + 1) < (unsigned)RS;
    int vx0 = (unsigned)ix < (unsigned)CS;
    int vx1 = (unsigned)(ix + 1) < (unsigned)CS;
    int cy0 = min(max(iy, 0), RS - 1), cy1 = min(max(iy + 1, 0), RS - 1);
    int cx0 = min(max(ix, 0), CS - 1), cx1 = min(max(ix + 1, 0), CS - 1);
    float wy0 = 1.0f - wy, wx0 = 1.0f - wx;
    float a00 = wy0 * wx0 * m * (float)(vy0 & vx0);
    float a01 = wy0 * wx * m * (float)(vy0 & vx1);
    float a10 = wy * wx0 * m * (float)(vy1 & vx0);
    float a11 = wy * wx * m * (float)(vy1 & vx1);
    int rc00 = cy0 * CS + cx0;
    int rc01 = cy0 * CS + cx1;
    int rc10 = cy1 * CS + cx0;
    int rc11 = cy1 * CS + cx1;
#pragma unroll
    for (int ch = 0; ch < 2; ++ch) {
      const int csl = ch * 4 + lq;
      short8 v00 = *(const short8*)(xs4 + rc00 * 9 + csl);
      short8 v01 = *(const short8*)(xs4 + rc01 * 9 + csl);
      short8 v10 = *(const short8*)(xs4 + rc10 * 9 + csl);
      short8 v11 = *(const short8*)(xs4 + rc11 * 9 + csl);
      short8 t;
#pragma unroll
      for (int j = 0; j < 8; ++j) {
        float sv = a00 * b2f((unsigned short)v00[j])
                 + a01 * b2f((unsigned short)v01[j])
                 + a10 * b2f((unsigned short)v10[j])
                 + a11 * b2f((unsigned short)v11[j]);
        t[j] = bfbits(sv);
      }
      const int sidx = kk * 2 + ch;
#pragma unroll
      for (int ot = 0; ot < 4; ++ot) {
        short8 bw = *(const short8*)(wf4 + (sidx * 4 + ot) * 64 + lane);
        acc[ot] = __builtin_amdgcn_mfma_f32_16x16x32_bf16(bw, t, acc[ot], 0, 0, 0);
      }
    }
  }

  // ---- Epilogue: ReLU -> fp32 -> global ----
#pragma unroll
  for (int ot = 0; ot < 4; ++ot) {
#pragma unroll
    for (int r = 0; r < 4; ++r) {
      int o = ot * 16 + lq * 4 + r;
      float v = fmaxf(acc[ot][r], 0.0f);
      out[((b * O_ + o) << 14) + (h << 7) + w] = v;
    }
  }
}

extern "C" void kernel_launch(void* const* d_in, const int* in_sizes, int n_in,
                              void* d_out, int out_size, void* d_ws, size_t ws_size,
                              hipStream_t stream) {
  const float* x   = (const float*)d_in[0];
  const float* ele = (const float*)d_in[1];
  const float* ow  = (const float*)d_in[2];
  const float* ob  = (const float*)d_in[3];
  const float* mw  = (const float*)d_in[4];
  const float* mb  = (const float*)d_in[5];
  const float* dw  = (const float*)d_in[6];
  __hip_bfloat16* wsb = (__hip_bfloat16*)d_ws;

  build_frags<<<180, 256, 0, stream>>>(dw, mw, wsb);
  deform_main<<<512, 512, 0, stream>>>(x, ele, ow, ob, mb, wsb,
                                       (float*)d_out);
}

// Round 5
// 39.039 us; speedup vs baseline: 1.7041x; 1.1347x over previous
//
#include <hip/hip_runtime.h>
#include <hip/hip_bf16.h>
#include <hip/hip_fp16.h>

typedef _Float16 half8 __attribute__((ext_vector_type(8)));
typedef _Float16 half2v __attribute__((ext_vector_type(2)));
typedef float f32x4 __attribute__((ext_vector_type(4)));

#define B_ 4
#define C_ 64
#define O_ 64
#define H_ 128
#define W_ 128
#define HT 8     // tile rows
#define WT 16    // tile cols
#define HALO 3
#define RS 14    // staged rows (HT + 2*HALO)
#define CS 22    // staged cols (WT + 2*HALO)
// xs layout: [pixel][ch], pixel stride 72 f16 = 144B = 9 half8/uint4 slots

// ---------------------------------------------------------------------------
// Kernel 0: pre-build fragment-ready f16 weights in workspace.
//  wf  (deform_w): 18 k-steps x 4 o-tiles x 64 lanes x 8 = 36864 f16
//     k-order: k = kk*64 + c ; s = kk*2 + ch ; lane holds A[o=ot*16+(l&15)][k0+(l>>4)*8+j]
//  wfm (mask_w padded to 16 rows): 18 k-steps x 64 lanes x 8 = 9216 f16
// ---------------------------------------------------------------------------
__global__ void build_frags(const float* __restrict__ dw,
                            const float* __restrict__ mw,
                            _Float16* __restrict__ wsb) {
  int t = blockIdx.x * 256 + threadIdx.x;
  if (t < 36864) {
    int j = t & 7, lane = (t >> 3) & 63, ot = (t >> 9) & 3, s = t >> 11;
    int kk = s >> 1, ch = s & 1;
    int o = ot * 16 + (lane & 15);
    int c = ch * 32 + ((lane >> 4) << 3) + j;
    wsb[t] = (_Float16)dw[(o * 64 + c) * 9 + kk];
  } else if (t < 46080) {
    int t2 = t - 36864;
    int j = t2 & 7, lane = (t2 >> 3) & 63, s = t2 >> 9;
    int km = lane & 15;
    int c = (s & 1) * 32 + ((lane >> 4) << 3) + j;
    int tap = s >> 1;
    float v = (km < 9) ? mw[(km * 64 + c) * 9 + tap] : 0.0f;
    wsb[t] = (_Float16)v;
  }
}

// ---------------------------------------------------------------------------
// Main fused kernel. 512 blocks x 512 threads (8 waves; wave = pixel row).
// LDS: 44352 (xs4) + 4608 (offl f16) + 4608 (maskl) = 53568 B
// ---------------------------------------------------------------------------
__global__ __launch_bounds__(512, 4)
void deform_main(const float* __restrict__ x,
                 const float* __restrict__ ele,
                 const float* __restrict__ ow,
                 const float* __restrict__ ob,
                 const float* __restrict__ mb,
                 const _Float16* __restrict__ wsb,
                 float* __restrict__ out) {
  __shared__ uint4 xs4[RS * CS * 9];       // 44352 B, f16 data
  __shared__ _Float16 offl[128 * 18];      //  4608 B
  __shared__ float maskl[128 * 9];         //  4608 B

  const int tid = threadIdx.x;
  const int lane = tid & 63;
  const int wv = tid >> 6;        // 0..7 = pixel row within tile
  const int pcl = lane & 15;      // pixel col within tile / MFMA col
  const int lq = lane >> 4;       // k-slice quadrant

  const int bid = blockIdx.x;
  const int b = bid >> 7;
  const int t7 = bid & 127;
  const int r0 = (t7 >> 3) * HT;   // 16 row-tiles
  const int c0 = (t7 & 7) * WT;    // 8 col-tiles

  // ---- Phase 1: stage x patch to LDS as f16, packed-pair writes ----------
  // thread t owns channels {2*(t>>4), 2*(t>>4)+1}, pixels (t&15)+16k.
  // LDS write bank = (36*p + c2) mod 32 -> 2-way across wave = conflict-free.
  {
    _Float16* xsb = (_Float16*)xs4;
    const int c2 = tid >> 4;               // 0..31
    const int pl = tid & 15;
    const float* xb0 = x + b * (C_ * H_ * W_) + (2 * c2) * (H_ * W_);
    const float* xb1 = xb0 + (H_ * W_);
    for (int p = pl; p < RS * CS; p += 16) {
      int row = (p * 2979) >> 16;          // p / 22 for p < 700
      int col = p - row * CS;
      int gy = r0 - HALO + row, gx = c0 - HALO + col;
      float v0 = 0.0f, v1 = 0.0f;
      if ((unsigned)gy < 128u && (unsigned)gx < 128u) {
        int gi = (gy << 7) + gx;
        v0 = xb0[gi];
        v1 = xb1[gi];
      }
      half2v hv = {(_Float16)v0, (_Float16)v1};
      *(half2v*)&xsb[p * 72 + 2 * c2] = hv;
    }
  }
  __syncthreads();

  // ---- Phase 2: offset conv (1->18ch 3x3), threads < 128, one px each ----
  if (tid < 128) {
    int pr = tid >> 4, pc = tid & 15;
    int h = r0 + pr, w = c0 + pc;
    float ev[9];
#pragma unroll
    for (int ty = 0; ty < 3; ++ty)
#pragma unroll
      for (int tx = 0; tx < 3; ++tx) {
        int gy = h - 1 + ty, gx = w - 1 + tx;
        float v = 0.0f;
        if ((unsigned)gy < 128u && (unsigned)gx < 128u)
          v = ele[b * (H_ * W_) + (gy << 7) + gx];
        ev[ty * 3 + tx] = v;
      }
#pragma unroll
    for (int ci = 0; ci < 18; ++ci) {
      float a = ob[ci];
#pragma unroll
      for (int tap = 0; tap < 9; ++tap) a += ev[tap] * ow[ci * 9 + tap];
      offl[tid * 18 + ci] = (_Float16)a;
    }
  }

  // ---- Phase 3: mask conv (64->9ch 3x3 + sigmoid) via f16 MFMA -----------
  {
    const half8* wfm8 = ((const half8*)wsb) + 4608;  // after 36864 f16
    f32x4 macc = {0.f, 0.f, 0.f, 0.f};
#pragma unroll
    for (int s = 0; s < 18; ++s) {
      const int tap = s >> 1;
      const int chalf = s & 1;
      const int ty = tap / 3, tx = tap - ty * 3;
      half8 aw = wfm8[s * 64 + lane];
      const int csl = chalf * 4 + lq;
      int rc = (wv + (HALO - 1) + ty) * CS + (pcl + (HALO - 1) + tx);
      half8 xv = *(const half8*)(xs4 + rc * 9 + csl);
      macc = __builtin_amdgcn_mfma_f32_16x16x32_f16(aw, xv, macc, 0, 0, 0);
    }
    int px = wv * 16 + pcl;
#pragma unroll
    for (int r = 0; r < 4; ++r) {
      int km = lq * 4 + r;
      if (km < 9) {
        float a = macc[r] + mb[km];
        float m = 1.0f / (1.0f + __expf(-a));
        maskl[px * 9 + km] = m;
      }
    }
  }
  __syncthreads();

  // ---- Phase 4: bilinear sampling (packed f16 blend) + MFMA --------------
  const half8* wf8 = (const half8*)wsb;
  f32x4 acc[4];
#pragma unroll
  for (int ot = 0; ot < 4; ++ot) {
    f32x4 z = {0.f, 0.f, 0.f, 0.f};
    acc[ot] = z;
  }

  const int px = wv * 16 + pcl;
  const int h = r0 + wv;
  const int w = c0 + pcl;

  for (int kk = 0; kk < 9; ++kk) {
    const int ky = kk / 3 - 1;
    const int kx = kk - (kk / 3) * 3 - 1;
    half2v o2 = *(const half2v*)&offl[px * 18 + kk * 2];
    float oy = (float)o2[0];
    float ox = (float)o2[1];
    float m = maskl[px * 9 + kk];
    float py = (float)(h + ky) + oy;
    float pxx = (float)(w + kx) + ox;
    float fy = floorf(py), fx = floorf(pxx);
    float wy = py - fy, wx = pxx - fx;
    int iy = (int)fy - r0 + HALO;
    int ix = (int)fx - c0 + HALO;
    int vy0 = (unsigned)iy < (unsigned)RS;
    int vy1 = (unsigned)(iy + 1) < (unsigned)RS;
    int vx0 = (unsigned)ix < (unsigned)CS;
    int vx1 = (unsigned)(ix + 1) < (unsigned)CS;
    int cy0 = min(max(iy, 0), RS - 1), cy1 = min(max(iy + 1, 0), RS - 1);
    int cx0 = min(max(ix, 0), CS - 1), cx1 = min(max(ix + 1, 0), CS - 1);
    float wy0 = 1.0f - wy, wx0 = 1.0f - wx;
    _Float16 a00 = (_Float16)(wy0 * wx0 * m * (float)(vy0 & vx0));
    _Float16 a01 = (_Float16)(wy0 * wx * m * (float)(vy0 & vx1));
    _Float16 a10 = (_Float16)(wy * wx0 * m * (float)(vy1 & vx0));
    _Float16 a11 = (_Float16)(wy * wx * m * (float)(vy1 & vx1));
    half8 a00s = {a00, a00, a00, a00, a00, a00, a00, a00};
    half8 a01s = {a01, a01, a01, a01, a01, a01, a01, a01};
    half8 a10s = {a10, a10, a10, a10, a10, a10, a10, a10};
    half8 a11s = {a11, a11, a11, a11, a11, a11, a11, a11};
    int rc00 = cy0 * CS + cx0;
    int rc01 = cy0 * CS + cx1;
    int rc10 = cy1 * CS + cx0;
    int rc11 = cy1 * CS + cx1;
#pragma unroll
    for (int ch = 0; ch < 2; ++ch) {
      const int csl = ch * 4 + lq;
      half8 v00 = *(const half8*)(xs4 + rc00 * 9 + csl);
      half8 v01 = *(const half8*)(xs4 + rc01 * 9 + csl);
      half8 v10 = *(const half8*)(xs4 + rc10 * 9 + csl);
      half8 v11 = *(const half8*)(xs4 + rc11 * 9 + csl);
      half8 t = v00 * a00s + v01 * a01s + v10 * a10s + v11 * a11s;
      const int sidx = kk * 2 + ch;
#pragma unroll
      for (int ot = 0; ot < 4; ++ot) {
        half8 bw = wf8[(sidx * 4 + ot) * 64 + lane];
        acc[ot] = __builtin_amdgcn_mfma_f32_16x16x32_f16(bw, t, acc[ot], 0, 0, 0);
      }
    }
  }

  // ---- Epilogue: ReLU -> fp32 -> global ----
#pragma unroll
  for (int ot = 0; ot < 4; ++ot) {
#pragma unroll
    for (int r = 0; r < 4; ++r) {
      int o = ot * 16 + lq * 4 + r;
      float v = fmaxf(acc[ot][r], 0.0f);
      out[((b * O_ + o) << 14) + (h << 7) + w] = v;
    }
  }
}

extern "C" void kernel_launch(void* const* d_in, const int* in_sizes, int n_in,
                              void* d_out, int out_size, void* d_ws, size_t ws_size,
                              hipStream_t stream) {
  const float* x   = (const float*)d_in[0];
  const float* ele = (const float*)d_in[1];
  const float* ow  = (const float*)d_in[2];
  const float* ob  = (const float*)d_in[3];
  const float* mw  = (const float*)d_in[4];
  const float* mb  = (const float*)d_in[5];
  const float* dw  = (const float*)d_in[6];
  _Float16* wsb = (_Float16*)d_ws;

  build_frags<<<180, 256, 0, stream>>>(dw, mw, wsb);
  deform_main<<<512, 512, 0, stream>>>(x, ele, ow, ob, mb, wsb,
                                       (float*)d_out);
}

// Round 6
// 32.291 us; speedup vs baseline: 2.0602x; 1.2090x over previous
//
#include <hip/hip_runtime.h>
#include <hip/hip_bf16.h>
#include <hip/hip_fp16.h>

typedef _Float16 half8 __attribute__((ext_vector_type(8)));
typedef _Float16 half2v __attribute__((ext_vector_type(2)));
typedef float f32x4 __attribute__((ext_vector_type(4)));

#define B_ 4
#define C_ 64
#define O_ 64
#define H_ 128
#define W_ 128
#define HT 8     // tile rows
#define WT 16    // tile cols
#define HALO 3
#define RS 14    // staged rows (HT + 2*HALO)
#define CS 22    // staged cols (WT + 2*HALO)
// xs layout: [pixel][ch], pixel stride 72 f16 = 144B = 9 half8/uint4 slots

__device__ __forceinline__ unsigned pkh(float lo, float hi) {
  half2v v = {(_Float16)lo, (_Float16)hi};
  return __builtin_bit_cast(unsigned, v);
}

// ---------------------------------------------------------------------------
// Kernel 0: pre-build fragment-ready f16 weights in workspace.
//  wf  (deform_w): 18 k-steps x 4 o-tiles x 64 lanes x 8 = 36864 f16
//  wfm (mask_w padded to 16 rows): 18 k-steps x 64 lanes x 8 = 9216 f16
// ---------------------------------------------------------------------------
__global__ void build_frags(const float* __restrict__ dw,
                            const float* __restrict__ mw,
                            _Float16* __restrict__ wsb) {
  int t = blockIdx.x * 256 + threadIdx.x;
  if (t < 36864) {
    int j = t & 7, lane = (t >> 3) & 63, ot = (t >> 9) & 3, s = t >> 11;
    int kk = s >> 1, ch = s & 1;
    int o = ot * 16 + (lane & 15);
    int c = ch * 32 + ((lane >> 4) << 3) + j;
    wsb[t] = (_Float16)dw[(o * 64 + c) * 9 + kk];
  } else if (t < 46080) {
    int t2 = t - 36864;
    int j = t2 & 7, lane = (t2 >> 3) & 63, s = t2 >> 9;
    int km = lane & 15;
    int c = (s & 1) * 32 + ((lane >> 4) << 3) + j;
    int tap = s >> 1;
    float v = (km < 9) ? mw[(km * 64 + c) * 9 + tap] : 0.0f;
    wsb[t] = (_Float16)v;
  }
}

// ---------------------------------------------------------------------------
// Main fused kernel. 512 blocks x 512 threads (8 waves; wave = pixel row).
// LDS: 44352 (xs) + 4608 (offl) + 2304 (maskl f16) + 9216 (cwb) + 4608 (crc)
//    = 65088 B  (< 64 KiB static limit; 2 blocks/CU)
// ---------------------------------------------------------------------------
__global__ __launch_bounds__(512, 4)
void deform_main(const float* __restrict__ x,
                 const float* __restrict__ ele,
                 const float* __restrict__ ow,
                 const float* __restrict__ ob,
                 const float* __restrict__ mb,
                 const _Float16* __restrict__ wsb,
                 float* __restrict__ out) {
  __shared__ uint4 xs4[RS * CS * 9];       // 44352 B, f16 data
  __shared__ _Float16 offl[128 * 18];      //  4608 B
  __shared__ _Float16 maskl[128 * 9];      //  2304 B
  __shared__ uint2 cwb[128 * 9];           //  9216 B  packed (a00,a01),(a10,a11)
  __shared__ unsigned crc[128 * 9];        //  4608 B  rc00 | drow<<16 | dcol<<24

  const int tid = threadIdx.x;
  const int lane = tid & 63;
  const int wv = tid >> 6;        // 0..7 = pixel row within tile
  const int pcl = lane & 15;      // pixel col within tile / MFMA col
  const int lq = lane >> 4;       // k-slice quadrant

  // XCD-bijective swizzle: consecutive decoded tiles land on the same XCD.
  const int bid = blockIdx.x;
  const int d = ((bid & 7) << 6) + (bid >> 3);   // 512 % 8 == 0 -> bijective
  const int b = d >> 7;
  const int t7 = d & 127;
  const int r0 = (t7 >> 3) * HT;   // 16 row-tiles
  const int c0 = (t7 & 7) * WT;    // 8 col-tiles

  // ---- Early: issue phase-2 ele loads (latency hidden under staging) -----
  float ev[9];
  {
    int tl = tid & 127;
    int pr = tl >> 4, pc = tl & 15;
    int h = r0 + pr, w = c0 + pc;
#pragma unroll
    for (int ty = 0; ty < 3; ++ty)
#pragma unroll
      for (int tx = 0; tx < 3; ++tx) {
        int gy = h - 1 + ty, gx = w - 1 + tx;
        float v = 0.0f;
        if ((unsigned)gy < 128u && (unsigned)gx < 128u)
          v = ele[b * (H_ * W_) + (gy << 7) + gx];
        ev[ty * 3 + tx] = v;
      }
  }

  // ---- Phase 1: stage x patch to LDS as f16, packed-pair writes ----------
  // thread t owns channels {2*(t>>4), 2*(t>>4)+1}, pixels (t&15)+16k.
  // LDS write bank = (36*p + c2) mod 32 -> 2-way across wave = conflict-free.
  {
    _Float16* xsb = (_Float16*)xs4;
    const int c2 = tid >> 4;               // 0..31
    const int pl = tid & 15;
    const float* xb0 = x + b * (C_ * H_ * W_) + (2 * c2) * (H_ * W_);
    const float* xb1 = xb0 + (H_ * W_);
    for (int p = pl; p < RS * CS; p += 16) {
      int row = (p * 2979) >> 16;          // p / 22 for p < 700
      int col = p - row * CS;
      int gy = r0 - HALO + row, gx = c0 - HALO + col;
      float v0 = 0.0f, v1 = 0.0f;
      if ((unsigned)gy < 128u && (unsigned)gx < 128u) {
        int gi = (gy << 7) + gx;
        v0 = xb0[gi];
        v1 = xb1[gi];
      }
      half2v hv = {(_Float16)v0, (_Float16)v1};
      *(half2v*)&xsb[p * 72 + 2 * c2] = hv;
    }
  }

  // ---- Phase 2: offset conv (1->18ch 3x3), threads < 128, one px each ----
  if (tid < 128) {
#pragma unroll
    for (int ci = 0; ci < 18; ++ci) {
      float a = ob[ci];
#pragma unroll
      for (int tap = 0; tap < 9; ++tap) a += ev[tap] * ow[ci * 9 + tap];
      offl[tid * 18 + ci] = (_Float16)a;
    }
  }
  __syncthreads();   // xs + offl ready

  // ---- Phase 3: mask conv (64->9ch 3x3 + sigmoid) via f16 MFMA -----------
  {
    const half8* wfm8 = ((const half8*)wsb) + 4608;  // after 36864 f16
    f32x4 macc = {0.f, 0.f, 0.f, 0.f};
#pragma unroll
    for (int s = 0; s < 18; ++s) {
      const int tap = s >> 1;
      const int chalf = s & 1;
      const int ty = tap / 3, tx = tap - ty * 3;
      half8 aw = wfm8[s * 64 + lane];
      const int csl = chalf * 4 + lq;
      int rc = (wv + (HALO - 1) + ty) * CS + (pcl + (HALO - 1) + tx);
      half8 xv = *(const half8*)(xs4 + rc * 9 + csl);
      macc = __builtin_amdgcn_mfma_f32_16x16x32_f16(aw, xv, macc, 0, 0, 0);
    }
    int px = wv * 16 + pcl;
#pragma unroll
    for (int r = 0; r < 4; ++r) {
      int km = lq * 4 + r;
      if (km < 9) {
        float a = macc[r] + mb[km];
        float m = 1.0f / (1.0f + __expf(-a));
        maskl[px * 9 + km] = (_Float16)m;
      }
    }
  }
  __syncthreads();   // maskl ready

  // ---- Phase 2b: bilinear coefficient precompute (all 512 threads) -------
  for (int it = tid; it < 128 * 9; it += 512) {
    int px = (it * 7282) >> 16;            // it / 9 for it < 1152
    int kk = it - px * 9;
    int pr = px >> 4, pc = px & 15;
    int h = r0 + pr, w = c0 + pc;
    int ky = kk / 3 - 1;
    int kx = kk - (kk / 3) * 3 - 1;
    half2v o2 = *(const half2v*)&offl[px * 18 + kk * 2];
    float m = (float)maskl[px * 9 + kk];
    float py = (float)(h + ky) + (float)o2[0];
    float pxx = (float)(w + kx) + (float)o2[1];
    float fy = floorf(py), fx = floorf(pxx);
    float wy = py - fy, wx = pxx - fx;
    int iy = (int)fy - r0 + HALO;
    int ix = (int)fx - c0 + HALO;
    int vy0 = (unsigned)iy < (unsigned)RS;
    int vy1 = (unsigned)(iy + 1) < (unsigned)RS;
    int vx0 = (unsigned)ix < (unsigned)CS;
    int vx1 = (unsigned)(ix + 1) < (unsigned)CS;
    int cy0 = min(max(iy, 0), RS - 1), cy1 = min(max(iy + 1, 0), RS - 1);
    int cx0 = min(max(ix, 0), CS - 1), cx1 = min(max(ix + 1, 0), CS - 1);
    float wy0 = 1.0f - wy, wx0 = 1.0f - wx;
    float a00 = wy0 * wx0 * m * (float)(vy0 & vx0);
    float a01 = wy0 * wx * m * (float)(vy0 & vx1);
    float a10 = wy * wx0 * m * (float)(vy1 & vx0);
    float a11 = wy * wx * m * (float)(vy1 & vx1);
    int rc00 = cy0 * CS + cx0;
    int drow = (cy1 - cy0) * CS;           // 0 or 22
    int dcol = cx1 - cx0;                  // 0 or 1
    uint2 cv;
    cv.x = pkh(a00, a01);
    cv.y = pkh(a10, a11);
    cwb[it] = cv;
    crc[it] = (unsigned)rc00 | ((unsigned)drow << 16) | ((unsigned)dcol << 24);
  }
  __syncthreads();   // coefficients ready

  // ---- Phase 4: streaming gather-blend + MFMA ----------------------------
  const half8* wf8 = (const half8*)wsb;
  f32x4 acc[4];
#pragma unroll
  for (int ot = 0; ot < 4; ++ot) {
    f32x4 z = {0.f, 0.f, 0.f, 0.f};
    acc[ot] = z;
  }

  const int px = wv * 16 + pcl;
  const int h = r0 + wv;
  const int w = c0 + pcl;

#pragma unroll
  for (int kk = 0; kk < 9; ++kk) {
    uint2 cv = cwb[px * 9 + kk];
    unsigned rv = crc[px * 9 + kk];
    int rc00 = rv & 0xFFFF;
    int drow = (rv >> 16) & 0xFF;
    int dcol = rv >> 24;
    int rc01 = rc00 + dcol;
    int rc10 = rc00 + drow;
    int rc11 = rc10 + dcol;
    half2v c01 = __builtin_bit_cast(half2v, cv.x);
    half2v c23 = __builtin_bit_cast(half2v, cv.y);
    _Float16 a00 = c01[0], a01 = c01[1], a10 = c23[0], a11 = c23[1];
    half8 a00s = {a00, a00, a00, a00, a00, a00, a00, a00};
    half8 a01s = {a01, a01, a01, a01, a01, a01, a01, a01};
    half8 a10s = {a10, a10, a10, a10, a10, a10, a10, a10};
    half8 a11s = {a11, a11, a11, a11, a11, a11, a11, a11};
#pragma unroll
    for (int ch = 0; ch < 2; ++ch) {
      const int csl = ch * 4 + lq;
      half8 v00 = *(const half8*)(xs4 + rc00 * 9 + csl);
      half8 v01 = *(const half8*)(xs4 + rc01 * 9 + csl);
      half8 v10 = *(const half8*)(xs4 + rc10 * 9 + csl);
      half8 v11 = *(const half8*)(xs4 + rc11 * 9 + csl);
      half8 t = v00 * a00s + v01 * a01s + v10 * a10s + v11 * a11s;
      const int sidx = kk * 2 + ch;
#pragma unroll
      for (int ot = 0; ot < 4; ++ot) {
        half8 bw = wf8[(sidx * 4 + ot) * 64 + lane];
        acc[ot] = __builtin_amdgcn_mfma_f32_16x16x32_f16(bw, t, acc[ot], 0, 0, 0);
      }
    }
  }

  // ---- Epilogue: ReLU -> fp32 -> global ----
#pragma unroll
  for (int ot = 0; ot < 4; ++ot) {
#pragma unroll
    for (int r = 0; r < 4; ++r) {
      int o = ot * 16 + lq * 4 + r;
      float v = fmaxf(acc[ot][r], 0.0f);
      out[((b * O_ + o) << 14) + (h << 7) + w] = v;
    }
  }
}

extern "C" void kernel_launch(void* const* d_in, const int* in_sizes, int n_in,
                              void* d_out, int out_size, void* d_ws, size_t ws_size,
                              hipStream_t stream) {
  const float* x   = (const float*)d_in[0];
  const float* ele = (const float*)d_in[1];
  const float* ow  = (const float*)d_in[2];
  const float* ob  = (const float*)d_in[3];
  const float* mw  = (const float*)d_in[4];
  const float* mb  = (const float*)d_in[5];
  const float* dw  = (const float*)d_in[6];
  _Float16* wsb = (_Float16*)d_ws;

  build_frags<<<180, 256, 0, stream>>>(dw, mw, wsb);
  deform_main<<<512, 512, 0, stream>>>(x, ele, ow, ob, mb, wsb,
                                       (float*)d_out);
}